// Round 2
// baseline (145.455 us; speedup 1.0000x reference)
//
#include <hip/hip_runtime.h>
#include <hip/hip_bf16.h>
#include <math.h>

#define N_FEAT 6272
#define DIM    128
#define M_BANK 30000
#define M_PAD  30080
#define NB     8
#define PH     28
#define PW     28
#define IMG    224
#define BM     256      // rows per block (4 waves x 64 rows)
#define BN     128      // bank cols per LDS tile
#define TPC    5
#define CHUNKS 47       // 47*5*128 = 30080
#define TILE_BYTES 32768

typedef __attribute__((ext_vector_type(8)))  __bf16 bf16x8_t;
typedef __attribute__((ext_vector_type(2)))  __bf16 bf16x2_t;
typedef __attribute__((ext_vector_type(16))) float  f32x16_t;
typedef __attribute__((ext_vector_type(4)))  float  f32x4_t;
typedef __attribute__((ext_vector_type(2)))  float  f32x2_t;

typedef const __attribute__((address_space(1))) unsigned int g_u32;
typedef __attribute__((address_space(3))) unsigned int l_u32;

// Bank prep: fp32 -> bf16, retiled into MFMA B-fragment order.
// Layout: tile t (128 cols) | k-slice s = k>>3 (16 slices) | col c (128) | 8 bf16.
// byte addr = t*32768 + s*2048 + c*16. Also per-row sum-of-squares (+inf pad).
__global__ __launch_bounds__(256) void prep_bank(const float* __restrict__ src,
                                                 unsigned char* __restrict__ mbt,
                                                 float* __restrict__ sq) {
    const int tid  = threadIdx.x;
    const int s    = tid & 15;          // k-slice
    const int rloc = tid >> 4;          // 16 rows per block
    const int r    = blockIdx.x * 16 + rloc;
    const bool valid = r < M_BANK;
    float x[8];
    if (valid) {
        f32x4_t v0 = *(const f32x4_t*)(src + (size_t)r * DIM + s * 8);
        f32x4_t v1 = *(const f32x4_t*)(src + (size_t)r * DIM + s * 8 + 4);
        x[0]=v0.x; x[1]=v0.y; x[2]=v0.z; x[3]=v0.w;
        x[4]=v1.x; x[5]=v1.y; x[6]=v1.z; x[7]=v1.w;
    } else {
        #pragma unroll
        for (int e = 0; e < 8; ++e) x[e] = 0.f;
    }
    float sum = 0.f;
    #pragma unroll
    for (int e = 0; e < 8; ++e) sum += x[e] * x[e];
    sum += __shfl_xor(sum, 1);
    sum += __shfl_xor(sum, 2);
    sum += __shfl_xor(sum, 4);
    sum += __shfl_xor(sum, 8);
    bf16x8_t p;
    #pragma unroll
    for (int e = 0; e < 8; ++e) p[e] = (__bf16)x[e];
    const size_t addr = (size_t)(r >> 7) * TILE_BYTES + s * 2048 + (r & 127) * 16;
    *(bf16x8_t*)(mbt + addr) = p;
    if (s == 0) sq[r] = valid ? sum : INFINITY;
}

// Feature prep: row-major bf16 + sum-of-squares + nn init (one wave per row).
__global__ __launch_bounds__(256) void prep_feat(const float* __restrict__ src,
                                                 __bf16* __restrict__ dst,
                                                 float* __restrict__ sq,
                                                 unsigned int* __restrict__ nn) {
    int wave = (blockIdx.x * blockDim.x + threadIdx.x) >> 6;
    int lane = threadIdx.x & 63;
    if (wave >= N_FEAT) return;
    f32x2_t v = *(const f32x2_t*)(src + (size_t)wave * DIM + lane * 2);
    float s = v.x * v.x + v.y * v.y;
    #pragma unroll
    for (int m = 1; m < 64; m <<= 1) s += __shfl_xor(s, m);
    bf16x2_t p; p.x = (__bf16)v.x; p.y = (__bf16)v.y;
    *(bf16x2_t*)(dst + (size_t)wave * DIM + lane * 2) = p;
    if (lane == 0) { sq[wave] = s; nn[wave] = 0x7f800000u; }
}

static __device__ __forceinline__ f32x16_t zero16() {
    f32x16_t z;
    #pragma unroll
    for (int j = 0; j < 16; ++j) z[j] = 0.f;
    return z;
}

// 4 waves, each owns 64 rows (two 32-row MFMA blocks). A in registers (K=128).
// Per tile: global_load_lds 32KB (linear, pre-tiled) -> conflict-free
// ds_read_b128 B-frags -> 32x32x16 MFMA -> fused (m2 - 2*dot) running min.
__global__ __launch_bounds__(256) void dist_min_kernel(
        const __bf16* __restrict__ fbb, const unsigned char* __restrict__ mbt,
        const float* __restrict__ f2, const float* __restrict__ m2,
        unsigned int* __restrict__ nn) {
    __shared__ __align__(16) unsigned char lds[TILE_BYTES];
    const int tid  = threadIdx.x;
    const int lane = tid & 63;
    const int w    = tid >> 6;
    const int c32  = lane & 31;    // MFMA col / A-row within 32-block
    const int h    = lane >> 5;    // k-half selector
    const int arow = blockIdx.x * BM + w * 64;

    // A fragments: afrag[m][kk] = A[arow+m*32+c32][kk*16 + h*8 .. +7]
    bf16x8_t afrag[2][8];
    #pragma unroll
    for (int m = 0; m < 2; ++m) {
        int row = arow + m * 32 + c32;
        if (row >= N_FEAT) row = N_FEAT - 1;   // tail clamp (results discarded)
        #pragma unroll
        for (int kk = 0; kk < 8; ++kk)
            afrag[m][kk] = *(const bf16x8_t*)(fbb + (size_t)row * DIM + kk * 16 + h * 8);
    }

    f32x16_t rmin0 = zero16(), rmin1 = zero16();
    #pragma unroll
    for (int j = 0; j < 16; ++j) { rmin0[j] = INFINITY; rmin1[j] = INFINITY; }

    for (int t = 0; t < TPC; ++t) {
        const int tile = blockIdx.y * TPC + t;
        __syncthreads();  // previous tile's reads complete before overwrite
        {
            const unsigned char* src = mbt + (size_t)tile * TILE_BYTES + w * 8192 + lane * 16;
            unsigned char* dstb = lds + w * 8192;
            #pragma unroll
            for (int i = 0; i < 8; ++i)
                __builtin_amdgcn_global_load_lds((g_u32*)(src + i * 1024),
                                                 (l_u32*)(dstb + i * 1024), 16, 0, 0);
        }
        __syncthreads();  // compiler drains vmcnt before barrier
        const int c0 = tile * BN;
        float m2v[4];
        #pragma unroll
        for (int n = 0; n < 4; ++n) m2v[n] = m2[c0 + n * 32 + c32];
        #pragma unroll
        for (int n = 0; n < 4; ++n) {
            f32x16_t acc0 = zero16(), acc1 = zero16();
            #pragma unroll
            for (int kk = 0; kk < 8; ++kk) {
                bf16x8_t b = *(const bf16x8_t*)(lds + (kk * 2 + h) * 2048 + n * 512 + c32 * 16);
                acc0 = __builtin_amdgcn_mfma_f32_32x32x16_bf16(afrag[0][kk], b, acc0, 0, 0, 0);
                acc1 = __builtin_amdgcn_mfma_f32_32x32x16_bf16(afrag[1][kk], b, acc1, 0, 0, 0);
            }
            #pragma unroll
            for (int j = 0; j < 16; ++j) {
                rmin0[j] = fminf(rmin0[j], m2v[n] - 2.0f * acc0[j]);
                rmin1[j] = fminf(rmin1[j], m2v[n] - 2.0f * acc1[j]);
            }
        }
    }

    // Epilogue: min across cols (lanes sharing h), then one atomic per row.
    #pragma unroll
    for (int m = 0; m < 2; ++m) {
        #pragma unroll
        for (int j = 0; j < 16; ++j) {
            float v = m ? rmin1[j] : rmin0[j];
            v = fminf(v, __shfl_xor(v, 1));
            v = fminf(v, __shfl_xor(v, 2));
            v = fminf(v, __shfl_xor(v, 4));
            v = fminf(v, __shfl_xor(v, 8));
            v = fminf(v, __shfl_xor(v, 16));
            if (c32 == 0) {
                int row = arow + m * 32 + (j & 3) + 8 * (j >> 2) + 4 * h;
                if (row < N_FEAT)
                    atomicMin(nn + row, __float_as_uint(v + f2[row]));
            }
        }
    }
}

__global__ void image_max_kernel(const unsigned int* __restrict__ nn,
                                 float* __restrict__ out) {
    __shared__ float wmax[4];
    int b = blockIdx.x;
    int tid = threadIdx.x;
    float v = -INFINITY;
    for (int i = tid; i < PH * PW; i += 256)
        v = fmaxf(v, __uint_as_float(nn[b * PH * PW + i]));
    #pragma unroll
    for (int m = 1; m < 64; m <<= 1) v = fmaxf(v, __shfl_xor(v, m));
    if ((tid & 63) == 0) wmax[tid >> 6] = v;
    __syncthreads();
    if (tid == 0) out[b] = fmaxf(fmaxf(wmax[0], wmax[1]), fmaxf(wmax[2], wmax[3]));
}

// Half-pixel bilinear 28x28 -> 224x224 with edge clamp (== jax bilinear resize).
__global__ void upsample_kernel(const unsigned int* __restrict__ nn,
                                float* __restrict__ up) {
    int idx = blockIdx.x * 256 + threadIdx.x;
    if (idx >= NB * IMG * IMG) return;
    int b = idx / (IMG * IMG);
    int rem = idx - b * (IMG * IMG);
    int y = rem / IMG;
    int x = rem - y * IMG;
    float sy = y * 0.125f - 0.4375f;
    float sx = x * 0.125f - 0.4375f;
    float fy = floorf(sy), fx = floorf(sx);
    float ty = sy - fy, tx = sx - fx;
    int y0 = (int)fy, x0 = (int)fx;
    int y1 = min(y0 + 1, PH - 1), x1 = min(x0 + 1, PW - 1);
    y0 = max(y0, 0); x0 = max(x0, 0);
    const unsigned int* p = nn + b * PH * PW;
    float v00 = __uint_as_float(p[y0 * PW + x0]);
    float v01 = __uint_as_float(p[y0 * PW + x1]);
    float v10 = __uint_as_float(p[y1 * PW + x0]);
    float v11 = __uint_as_float(p[y1 * PW + x1]);
    float v0 = v00 + tx * (v01 - v00);
    float v1 = v10 + tx * (v11 - v10);
    up[idx] = v0 + ty * (v1 - v0);
}

extern "C" void kernel_launch(void* const* d_in, const int* in_sizes, int n_in,
                              void* d_out, int out_size, void* d_ws, size_t ws_size,
                              hipStream_t stream) {
    const float* feat = (const float*)d_in[0];   // [6272,128] f32
    const float* bank = (const float*)d_in[1];   // [30000,128] f32
    char* ws = (char*)d_ws;
    // workspace layout (same total as round 1: 9,476,608 bytes)
    unsigned char* mbt = (unsigned char*)(ws + 0);     // 30080*128*2 = 7,700,480 (tiled)
    __bf16*        fbb = (__bf16*)(ws + 7700480);      // 6272*128*2  = 1,605,632
    float*         m2  = (float*)(ws + 9306112);       // 30080*4
    float*         f2  = (float*)(ws + 9426432);       // 6272*4
    unsigned int*  nn  = (unsigned int*)(ws + 9451520);// 6272*4
    float* out_scores = (float*)d_out;                 // [8]
    float* out_up     = out_scores + NB;               // [8,224,224]

    hipLaunchKernelGGL(prep_bank, dim3(M_PAD / 16), dim3(256), 0, stream, bank, mbt, m2);
    hipLaunchKernelGGL(prep_feat, dim3(N_FEAT / 4), dim3(256), 0, stream, feat, fbb, f2, nn);
    hipLaunchKernelGGL(dist_min_kernel, dim3((N_FEAT + BM - 1) / BM, CHUNKS), dim3(256), 0,
                       stream, fbb, mbt, f2, m2, nn);
    hipLaunchKernelGGL(image_max_kernel, dim3(NB), dim3(256), 0, stream, nn, out_scores);
    hipLaunchKernelGGL(upsample_kernel, dim3((NB * IMG * IMG + 255) / 256), dim3(256), 0,
                       stream, nn, out_up);
}

// Round 3
// 108.232 us; speedup vs baseline: 1.3439x; 1.3439x over previous
//
#include <hip/hip_runtime.h>
#include <hip/hip_bf16.h>
#include <math.h>

#define N_FEAT 6272
#define DIM    128
#define M_BANK 30000
#define M_PAD  30080
#define NB     8
#define PH     28
#define PW     28
#define IMG    224
#define BM     256      // rows per block (4 waves x 64 rows)
#define BN     128      // bank cols per LDS tile
#define TPC    5
#define CHUNKS 47       // 47*5*128 = 30080
#define TILE_BYTES 32768

typedef __attribute__((ext_vector_type(8)))  __bf16 bf16x8_t;
typedef __attribute__((ext_vector_type(2)))  __bf16 bf16x2_t;
typedef __attribute__((ext_vector_type(16))) float  f32x16_t;
typedef __attribute__((ext_vector_type(4)))  float  f32x4_t;
typedef __attribute__((ext_vector_type(2)))  float  f32x2_t;

typedef const __attribute__((address_space(1))) unsigned int g_u32;
typedef __attribute__((address_space(3))) unsigned int l_u32;

// Bank prep: fp32 -> bf16, retiled into MFMA B-fragment order.
// Layout: tile t (128 cols) | k-slice s = k>>3 (16 slices) | col c (128) | 8 bf16.
// byte addr = t*32768 + s*2048 + c*16. Also per-row sum-of-squares (+inf pad).
__global__ __launch_bounds__(256) void prep_bank(const float* __restrict__ src,
                                                 unsigned char* __restrict__ mbt,
                                                 float* __restrict__ sq) {
    const int tid  = threadIdx.x;
    const int s    = tid & 15;          // k-slice
    const int rloc = tid >> 4;          // 16 rows per block
    const int r    = blockIdx.x * 16 + rloc;
    const bool valid = r < M_BANK;
    float x[8];
    if (valid) {
        f32x4_t v0 = *(const f32x4_t*)(src + (size_t)r * DIM + s * 8);
        f32x4_t v1 = *(const f32x4_t*)(src + (size_t)r * DIM + s * 8 + 4);
        x[0]=v0.x; x[1]=v0.y; x[2]=v0.z; x[3]=v0.w;
        x[4]=v1.x; x[5]=v1.y; x[6]=v1.z; x[7]=v1.w;
    } else {
        #pragma unroll
        for (int e = 0; e < 8; ++e) x[e] = 0.f;
    }
    float sum = 0.f;
    #pragma unroll
    for (int e = 0; e < 8; ++e) sum += x[e] * x[e];
    sum += __shfl_xor(sum, 1);
    sum += __shfl_xor(sum, 2);
    sum += __shfl_xor(sum, 4);
    sum += __shfl_xor(sum, 8);
    bf16x8_t p;
    #pragma unroll
    for (int e = 0; e < 8; ++e) p[e] = (__bf16)x[e];
    const size_t addr = (size_t)(r >> 7) * TILE_BYTES + s * 2048 + (r & 127) * 16;
    *(bf16x8_t*)(mbt + addr) = p;
    if (s == 0) sq[r] = valid ? sum : INFINITY;
}

// Feature prep: row-major bf16 + sum-of-squares + nn init (one wave per row).
__global__ __launch_bounds__(256) void prep_feat(const float* __restrict__ src,
                                                 __bf16* __restrict__ dst,
                                                 float* __restrict__ sq,
                                                 unsigned int* __restrict__ nn) {
    int wave = (blockIdx.x * blockDim.x + threadIdx.x) >> 6;
    int lane = threadIdx.x & 63;
    if (wave >= N_FEAT) return;
    f32x2_t v = *(const f32x2_t*)(src + (size_t)wave * DIM + lane * 2);
    float s = v.x * v.x + v.y * v.y;
    #pragma unroll
    for (int m = 1; m < 64; m <<= 1) s += __shfl_xor(s, m);
    bf16x2_t p; p.x = (__bf16)v.x; p.y = (__bf16)v.y;
    *(bf16x2_t*)(dst + (size_t)wave * DIM + lane * 2) = p;
    if (lane == 0) { sq[wave] = s; nn[wave] = 0x7f800000u; }
}

static __device__ __forceinline__ f32x16_t zero16() {
    f32x16_t z;
    #pragma unroll
    for (int j = 0; j < 16; ++j) z[j] = 0.f;
    return z;
}

// 4 waves x 64 rows, A in registers (K=128 total). Double-buffered LDS:
// issue next tile's global_load_lds BEFORE compute, one barrier per tile
// (its vmcnt(0) drain lands after compute has hidden the stage latency).
// #pragma unroll 1 on the n-loop keeps one (acc0,acc1) pair live -> ~2 waves/SIMD.
__global__ __launch_bounds__(256) void dist_min_kernel(
        const __bf16* __restrict__ fbb, const unsigned char* __restrict__ mbt,
        const float* __restrict__ f2, const float* __restrict__ m2,
        unsigned int* __restrict__ nn) {
    __shared__ __align__(16) unsigned char lds[2 * TILE_BYTES];
    const int tid  = threadIdx.x;
    const int lane = tid & 63;
    const int w    = tid >> 6;
    const int c32  = lane & 31;    // MFMA col / A-row within 32-block
    const int h    = lane >> 5;    // k-half selector
    const int arow = blockIdx.x * BM + w * 64;

    // A fragments: afrag[m][kk] = A[arow+m*32+c32][kk*16 + h*8 .. +7]
    bf16x8_t afrag[2][8];
    #pragma unroll
    for (int m = 0; m < 2; ++m) {
        int row = arow + m * 32 + c32;
        if (row >= N_FEAT) row = N_FEAT - 1;   // tail clamp (results discarded)
        #pragma unroll
        for (int kk = 0; kk < 8; ++kk)
            afrag[m][kk] = *(const bf16x8_t*)(fbb + (size_t)row * DIM + kk * 16 + h * 8);
    }

    f32x16_t rmin0 = zero16(), rmin1 = zero16();
    #pragma unroll
    for (int j = 0; j < 16; ++j) { rmin0[j] = INFINITY; rmin1[j] = INFINITY; }

    const int tile0 = blockIdx.y * TPC;
    // prologue: stage tile 0 into buffer 0
    {
        const unsigned char* src = mbt + (size_t)tile0 * TILE_BYTES + w * 8192 + lane * 16;
        unsigned char* dstb = lds + w * 8192;
        #pragma unroll
        for (int i = 0; i < 8; ++i)
            __builtin_amdgcn_global_load_lds((g_u32*)(src + i * 1024),
                                             (l_u32*)(dstb + i * 1024), 16, 0, 0);
    }
    __syncthreads();

    int cur = 0;
    #pragma unroll 1
    for (int t = 0; t < TPC; ++t) {
        const int tile = tile0 + t;
        // issue next tile's stage into the other buffer (hidden under compute)
        if (t + 1 < TPC) {
            const unsigned char* src = mbt + (size_t)(tile + 1) * TILE_BYTES + w * 8192 + lane * 16;
            unsigned char* dstb = lds + (cur ^ 1) * TILE_BYTES + w * 8192;
            #pragma unroll
            for (int i = 0; i < 8; ++i)
                __builtin_amdgcn_global_load_lds((g_u32*)(src + i * 1024),
                                                 (l_u32*)(dstb + i * 1024), 16, 0, 0);
        }
        const unsigned char* buf = lds + cur * TILE_BYTES;
        const int c0 = tile * BN;
        #pragma unroll 1
        for (int n = 0; n < 4; ++n) {
            const float m2c = m2[c0 + n * 32 + c32];
            f32x16_t acc0 = zero16(), acc1 = zero16();
            #pragma unroll
            for (int kk = 0; kk < 8; ++kk) {
                bf16x8_t b = *(const bf16x8_t*)(buf + (kk * 2 + h) * 2048 + n * 512 + c32 * 16);
                acc0 = __builtin_amdgcn_mfma_f32_32x32x16_bf16(afrag[0][kk], b, acc0, 0, 0, 0);
                acc1 = __builtin_amdgcn_mfma_f32_32x32x16_bf16(afrag[1][kk], b, acc1, 0, 0, 0);
            }
            #pragma unroll
            for (int j = 0; j < 16; ++j) {
                rmin0[j] = fminf(rmin0[j], m2c - 2.0f * acc0[j]);
                rmin1[j] = fminf(rmin1[j], m2c - 2.0f * acc1[j]);
            }
        }
        __syncthreads();   // drains vmcnt -> next tile staged; buf[cur] free for reuse
        cur ^= 1;
    }

    // Epilogue: min across cols (lanes sharing h), then one atomic per row.
    #pragma unroll
    for (int m = 0; m < 2; ++m) {
        #pragma unroll
        for (int j = 0; j < 16; ++j) {
            float v = m ? rmin1[j] : rmin0[j];
            v = fminf(v, __shfl_xor(v, 1));
            v = fminf(v, __shfl_xor(v, 2));
            v = fminf(v, __shfl_xor(v, 4));
            v = fminf(v, __shfl_xor(v, 8));
            v = fminf(v, __shfl_xor(v, 16));
            if (c32 == 0) {
                int row = arow + m * 32 + (j & 3) + 8 * (j >> 2) + 4 * h;
                if (row < N_FEAT)
                    atomicMin(nn + row, __float_as_uint(v + f2[row]));
            }
        }
    }
}

__global__ void image_max_kernel(const unsigned int* __restrict__ nn,
                                 float* __restrict__ out) {
    __shared__ float wmax[4];
    int b = blockIdx.x;
    int tid = threadIdx.x;
    float v = -INFINITY;
    for (int i = tid; i < PH * PW; i += 256)
        v = fmaxf(v, __uint_as_float(nn[b * PH * PW + i]));
    #pragma unroll
    for (int m = 1; m < 64; m <<= 1) v = fmaxf(v, __shfl_xor(v, m));
    if ((tid & 63) == 0) wmax[tid >> 6] = v;
    __syncthreads();
    if (tid == 0) out[b] = fmaxf(fmaxf(wmax[0], wmax[1]), fmaxf(wmax[2], wmax[3]));
}

// Half-pixel bilinear 28x28 -> 224x224 with edge clamp (== jax bilinear resize).
__global__ void upsample_kernel(const unsigned int* __restrict__ nn,
                                float* __restrict__ up) {
    int idx = blockIdx.x * 256 + threadIdx.x;
    if (idx >= NB * IMG * IMG) return;
    int b = idx / (IMG * IMG);
    int rem = idx - b * (IMG * IMG);
    int y = rem / IMG;
    int x = rem - y * IMG;
    float sy = y * 0.125f - 0.4375f;
    float sx = x * 0.125f - 0.4375f;
    float fy = floorf(sy), fx = floorf(sx);
    float ty = sy - fy, tx = sx - fx;
    int y0 = (int)fy, x0 = (int)fx;
    int y1 = min(y0 + 1, PH - 1), x1 = min(x0 + 1, PW - 1);
    y0 = max(y0, 0); x0 = max(x0, 0);
    const unsigned int* p = nn + b * PH * PW;
    float v00 = __uint_as_float(p[y0 * PW + x0]);
    float v01 = __uint_as_float(p[y0 * PW + x1]);
    float v10 = __uint_as_float(p[y1 * PW + x0]);
    float v11 = __uint_as_float(p[y1 * PW + x1]);
    float v0 = v00 + tx * (v01 - v00);
    float v1 = v10 + tx * (v11 - v10);
    up[idx] = v0 + ty * (v1 - v0);
}

extern "C" void kernel_launch(void* const* d_in, const int* in_sizes, int n_in,
                              void* d_out, int out_size, void* d_ws, size_t ws_size,
                              hipStream_t stream) {
    const float* feat = (const float*)d_in[0];   // [6272,128] f32
    const float* bank = (const float*)d_in[1];   // [30000,128] f32
    char* ws = (char*)d_ws;
    unsigned char* mbt = (unsigned char*)(ws + 0);     // 30080*128*2 = 7,700,480 (tiled)
    __bf16*        fbb = (__bf16*)(ws + 7700480);      // 6272*128*2  = 1,605,632
    float*         m2  = (float*)(ws + 9306112);       // 30080*4
    float*         f2  = (float*)(ws + 9426432);       // 6272*4
    unsigned int*  nn  = (unsigned int*)(ws + 9451520);// 6272*4
    float* out_scores = (float*)d_out;                 // [8]
    float* out_up     = out_scores + NB;               // [8,224,224]

    hipLaunchKernelGGL(prep_bank, dim3(M_PAD / 16), dim3(256), 0, stream, bank, mbt, m2);
    hipLaunchKernelGGL(prep_feat, dim3(N_FEAT / 4), dim3(256), 0, stream, feat, fbb, f2, nn);
    hipLaunchKernelGGL(dist_min_kernel, dim3((N_FEAT + BM - 1) / BM, CHUNKS), dim3(256), 0,
                       stream, fbb, mbt, f2, m2, nn);
    hipLaunchKernelGGL(image_max_kernel, dim3(NB), dim3(256), 0, stream, nn, out_scores);
    hipLaunchKernelGGL(upsample_kernel, dim3((NB * IMG * IMG + 255) / 256), dim3(256), 0,
                       stream, nn, out_up);
}

// Round 4
// 71.282 us; speedup vs baseline: 2.0406x; 1.5184x over previous
//
#include <hip/hip_runtime.h>
#include <hip/hip_bf16.h>
#include <math.h>

#define N_FEAT 6272
#define DIM    128
#define M_BANK 30000
#define M_PAD  30080
#define NB     8
#define PH     28
#define PW     28
#define IMG    224
#define BM     128      // 4 waves x 32 rows (2 mb-blocks of 16)
#define BN     128      // bank cols per LDS tile
#define TPC    5
#define CHUNKS 47       // 47*5*128 = 30080
#define TILE_BYTES 32768

typedef __attribute__((ext_vector_type(8)))  __bf16 bf16x8_t;
typedef __attribute__((ext_vector_type(2)))  __bf16 bf16x2_t;
typedef __attribute__((ext_vector_type(4)))  float  f32x4_t;
typedef __attribute__((ext_vector_type(2)))  float  f32x2_t;

typedef const __attribute__((address_space(1))) unsigned int g_u32;
typedef __attribute__((address_space(3))) unsigned int l_u32;

// Bank prep: fp32 -> bf16, retiled into MFMA B-fragment order.
// Layout: tile t (128 cols) | k-slice s = k>>3 (16 slices) | col c (128) | 8 bf16.
// byte addr = t*32768 + s*2048 + c*16. Also per-row sum-of-squares (+inf pad).
__global__ __launch_bounds__(256) void prep_bank(const float* __restrict__ src,
                                                 unsigned char* __restrict__ mbt,
                                                 float* __restrict__ sq) {
    const int tid  = threadIdx.x;
    const int s    = tid & 15;          // k-slice
    const int rloc = tid >> 4;          // 16 rows per block
    const int r    = blockIdx.x * 16 + rloc;
    const bool valid = r < M_BANK;
    float x[8];
    if (valid) {
        f32x4_t v0 = *(const f32x4_t*)(src + (size_t)r * DIM + s * 8);
        f32x4_t v1 = *(const f32x4_t*)(src + (size_t)r * DIM + s * 8 + 4);
        x[0]=v0.x; x[1]=v0.y; x[2]=v0.z; x[3]=v0.w;
        x[4]=v1.x; x[5]=v1.y; x[6]=v1.z; x[7]=v1.w;
    } else {
        #pragma unroll
        for (int e = 0; e < 8; ++e) x[e] = 0.f;
    }
    float sum = 0.f;
    #pragma unroll
    for (int e = 0; e < 8; ++e) sum += x[e] * x[e];
    sum += __shfl_xor(sum, 1);
    sum += __shfl_xor(sum, 2);
    sum += __shfl_xor(sum, 4);
    sum += __shfl_xor(sum, 8);
    bf16x8_t p;
    #pragma unroll
    for (int e = 0; e < 8; ++e) p[e] = (__bf16)x[e];
    const size_t addr = (size_t)(r >> 7) * TILE_BYTES + s * 2048 + (r & 127) * 16;
    *(bf16x8_t*)(mbt + addr) = p;
    if (s == 0) sq[r] = valid ? sum : INFINITY;
}

// Feature prep: row-major bf16 + sum-of-squares + nn init (one wave per row).
__global__ __launch_bounds__(256) void prep_feat(const float* __restrict__ src,
                                                 __bf16* __restrict__ dst,
                                                 float* __restrict__ sq,
                                                 unsigned int* __restrict__ nn) {
    int wave = (blockIdx.x * blockDim.x + threadIdx.x) >> 6;
    int lane = threadIdx.x & 63;
    if (wave >= N_FEAT) return;
    f32x2_t v = *(const f32x2_t*)(src + (size_t)wave * DIM + lane * 2);
    float s = v.x * v.x + v.y * v.y;
    #pragma unroll
    for (int m = 1; m < 64; m <<= 1) s += __shfl_xor(s, m);
    bf16x2_t p; p.x = (__bf16)v.x; p.y = (__bf16)v.y;
    *(bf16x2_t*)(dst + (size_t)wave * DIM + lane * 2) = p;
    if (lane == 0) { sq[wave] = s; nn[wave] = 0x7f800000u; }
}

// Occupancy-first dist+min: 4 waves x 32 rows, 16x16x32 MFMA, single 32KB LDS
// buffer, 2 barriers/tile (m97 structure). ~90 VGPR -> 4 waves/SIMD, 4 blocks/CU;
// cross-block overlap hides the stage drain. A in registers (K=128 total).
__global__ __launch_bounds__(256, 4) void dist_min_kernel(
        const __bf16* __restrict__ fbb, const unsigned char* __restrict__ mbt,
        const float* __restrict__ f2, const float* __restrict__ m2,
        unsigned int* __restrict__ nn) {
    __shared__ __align__(16) unsigned char lds[TILE_BYTES];
    const int tid  = threadIdx.x;
    const int lane = tid & 63;
    const int w    = tid >> 6;
    const int c16  = lane & 15;   // A-row16 / B-col16 / C-col
    const int kq   = lane >> 4;   // k-quarter (8 elems each)
    const int arow = blockIdx.x * BM + w * 32;

    // A fragments: afrag[mb][kk] = A[arow+mb*16+c16][kk*32 + kq*8 .. +7]
    bf16x8_t afrag[2][4];
    #pragma unroll
    for (int mb = 0; mb < 2; ++mb)
        #pragma unroll
        for (int kk = 0; kk < 4; ++kk)
            afrag[mb][kk] = *(const bf16x8_t*)(fbb + (size_t)(arow + mb * 16 + c16) * DIM
                                               + kk * 32 + kq * 8);

    float rmin[2][4];
    #pragma unroll
    for (int mb = 0; mb < 2; ++mb)
        #pragma unroll
        for (int j = 0; j < 4; ++j) rmin[mb][j] = INFINITY;

    const int tile0 = blockIdx.y * TPC;
    for (int t = 0; t < TPC; ++t) {
        const int tile = tile0 + t;
        // Stage 32KB tile: linear global -> linear LDS (pre-tiled layout).
        const unsigned char* src = mbt + (size_t)tile * TILE_BYTES + tid * 16;
        unsigned char* dst = lds + tid * 16;
        #pragma unroll
        for (int i = 0; i < 8; ++i)
            __builtin_amdgcn_global_load_lds((g_u32*)(src + i * 4096),
                                             (l_u32*)(dst + i * 4096), 16, 0, 0);
        __syncthreads();   // vmcnt(0) drain: tile staged

        const int c0 = tile * BN;
        float m2v[8];
        #pragma unroll
        for (int n = 0; n < 8; ++n) m2v[n] = m2[c0 + n * 16 + c16];

        #pragma unroll
        for (int n = 0; n < 8; ++n) {
            f32x4_t acc0 = {0.f, 0.f, 0.f, 0.f};
            f32x4_t acc1 = {0.f, 0.f, 0.f, 0.f};
            #pragma unroll
            for (int kk = 0; kk < 4; ++kk) {
                bf16x8_t b = *(const bf16x8_t*)(lds + (kk * 4 + kq) * 2048
                                                + (n * 16 + c16) * 16);
                acc0 = __builtin_amdgcn_mfma_f32_16x16x32_bf16(afrag[0][kk], b, acc0, 0, 0, 0);
                acc1 = __builtin_amdgcn_mfma_f32_16x16x32_bf16(afrag[1][kk], b, acc1, 0, 0, 0);
            }
            #pragma unroll
            for (int j = 0; j < 4; ++j) {
                rmin[0][j] = fminf(rmin[0][j], fmaf(-2.f, acc0[j], m2v[n]));
                rmin[1][j] = fminf(rmin[1][j], fmaf(-2.f, acc1[j], m2v[n]));
            }
        }
        __syncthreads();   // all reads done before next tile's stage overwrites
    }

    // Epilogue: min across the 16 col-lanes, add f2, one atomic per row.
    #pragma unroll
    for (int mb = 0; mb < 2; ++mb)
        #pragma unroll
        for (int j = 0; j < 4; ++j) {
            float v = rmin[mb][j];
            v = fminf(v, __shfl_xor(v, 1));
            v = fminf(v, __shfl_xor(v, 2));
            v = fminf(v, __shfl_xor(v, 4));
            v = fminf(v, __shfl_xor(v, 8));
            if (c16 == 0) {
                int row = arow + mb * 16 + kq * 4 + j;
                atomicMin(nn + row, __float_as_uint(v + f2[row]));
            }
        }
}

__global__ void image_max_kernel(const unsigned int* __restrict__ nn,
                                 float* __restrict__ out) {
    __shared__ float wmax[4];
    int b = blockIdx.x;
    int tid = threadIdx.x;
    float v = -INFINITY;
    for (int i = tid; i < PH * PW; i += 256)
        v = fmaxf(v, __uint_as_float(nn[b * PH * PW + i]));
    #pragma unroll
    for (int m = 1; m < 64; m <<= 1) v = fmaxf(v, __shfl_xor(v, m));
    if ((tid & 63) == 0) wmax[tid >> 6] = v;
    __syncthreads();
    if (tid == 0) out[b] = fmaxf(fmaxf(wmax[0], wmax[1]), fmaxf(wmax[2], wmax[3]));
}

// Half-pixel bilinear 28x28 -> 224x224 with edge clamp (== jax bilinear resize).
__global__ void upsample_kernel(const unsigned int* __restrict__ nn,
                                float* __restrict__ up) {
    int idx = blockIdx.x * 256 + threadIdx.x;
    if (idx >= NB * IMG * IMG) return;
    int b = idx / (IMG * IMG);
    int rem = idx - b * (IMG * IMG);
    int y = rem / IMG;
    int x = rem - y * IMG;
    float sy = y * 0.125f - 0.4375f;
    float sx = x * 0.125f - 0.4375f;
    float fy = floorf(sy), fx = floorf(sx);
    float ty = sy - fy, tx = sx - fx;
    int y0 = (int)fy, x0 = (int)fx;
    int y1 = min(y0 + 1, PH - 1), x1 = min(x0 + 1, PW - 1);
    y0 = max(y0, 0); x0 = max(x0, 0);
    const unsigned int* p = nn + b * PH * PW;
    float v00 = __uint_as_float(p[y0 * PW + x0]);
    float v01 = __uint_as_float(p[y0 * PW + x1]);
    float v10 = __uint_as_float(p[y1 * PW + x0]);
    float v11 = __uint_as_float(p[y1 * PW + x1]);
    float v0 = v00 + tx * (v01 - v00);
    float v1 = v10 + tx * (v11 - v10);
    up[idx] = v0 + ty * (v1 - v0);
}

extern "C" void kernel_launch(void* const* d_in, const int* in_sizes, int n_in,
                              void* d_out, int out_size, void* d_ws, size_t ws_size,
                              hipStream_t stream) {
    const float* feat = (const float*)d_in[0];   // [6272,128] f32
    const float* bank = (const float*)d_in[1];   // [30000,128] f32
    char* ws = (char*)d_ws;
    unsigned char* mbt = (unsigned char*)(ws + 0);     // 30080*128*2 = 7,700,480 (tiled)
    __bf16*        fbb = (__bf16*)(ws + 7700480);      // 6272*128*2  = 1,605,632
    float*         m2  = (float*)(ws + 9306112);       // 30080*4
    float*         f2  = (float*)(ws + 9426432);       // 6272*4
    unsigned int*  nn  = (unsigned int*)(ws + 9451520);// 6272*4
    float* out_scores = (float*)d_out;                 // [8]
    float* out_up     = out_scores + NB;               // [8,224,224]

    hipLaunchKernelGGL(prep_bank, dim3(M_PAD / 16), dim3(256), 0, stream, bank, mbt, m2);
    hipLaunchKernelGGL(prep_feat, dim3(N_FEAT / 4), dim3(256), 0, stream, feat, fbb, f2, nn);
    hipLaunchKernelGGL(dist_min_kernel, dim3(N_FEAT / BM, CHUNKS), dim3(256), 0,
                       stream, fbb, mbt, f2, m2, nn);
    hipLaunchKernelGGL(image_max_kernel, dim3(NB), dim3(256), 0, stream, nn, out_scores);
    hipLaunchKernelGGL(upsample_kernel, dim3((NB * IMG * IMG + 255) / 256), dim3(256), 0,
                       stream, nn, out_up);
}